// Round 21
// baseline (47.874 us; speedup 1.0000x reference)
//
#include <hip/hip_runtime.h>
#include <cstddef>

#define T_LEN 4096
#define BATCH 4
#define HID   1024
#define NS    16
#define ROWS  (BATCH*T_LEN)   // 16384
#define CHUNK 32
#define NCH   (T_LEN/CHUNK)   // 128

// workspace float offsets
#define OFF_P    1024     // P_j = A_d^(j+1), j=0..31   [32][16][16]
#define OFF_Q    32768    // Q_k = (A_d^32)^k, k=0..127 [128][16][16]
#define OFF_U    65536    // local states [16384][16]
#define OFF_LEND 327680   // chunk-end local states [4][128][16]

typedef __bf16 v8bf  __attribute__((ext_vector_type(8)));
typedef float  f32x4 __attribute__((ext_vector_type(4)));

// LDS-only barrier: does NOT drain vmcnt -> global loads stay in flight.
#define LDS_BAR() do { \
    __builtin_amdgcn_sched_barrier(0); \
    asm volatile("s_waitcnt lgkmcnt(0)" ::: "memory"); \
    __builtin_amdgcn_s_barrier(); \
    __builtin_amdgcn_sched_barrier(0); } while (0)

// ---------- K1 fused: full-x prefetch, setup + table chains under the stream
//            (lgkmcnt-only barriers), streaming y = x @ B^T, X-transform + scan;
//            blocks 0..159 emit one P/Q entry (store deferred to end) ----------
__global__ __launch_bounds__(512, 4) void k1_fused(const float* __restrict__ x,
                                                   const float* __restrict__ A,
                                                   const float* __restrict__ B,
                                                   const float* __restrict__ log_dt,
                                                   float* __restrict__ ws) {
    __shared__ __align__(16) float red[2048];      // setup scratch -> MFMA tiles (8KB)
    __shared__ __align__(16) float usy[512];       // y values
    __shared__ __align__(16) float us[512];        // u -> local states
    __shared__ float Adl[256], Xl[256];            // 2KB persistent
    __shared__ __align__(16) float tbl[3840];      // table scratch (15KB)
    const int tid  = threadIdx.x;
    const int w    = tid >> 6;
    const int lane = tid & 63;
    const int bid  = blockIdx.x;
    const int row0 = bid * 32;
    const int rhalf = w & 1;           // 16-row half
    const int kq    = w >> 1;          // 256-wide K slice
    const int lr = lane & 15;
    const int hi = lane >> 4;
    const int r16 = (tid >> 4) & 15, c16 = tid & 15;
    const float ident = (r16 == c16) ? 1.f : 0.f;

    // ---- prefetch: setup scalars first, then ALL x of this slice (16 float4)
    //      and shot-A of B; everything stays in flight through setup+tables ----
    const float ldt0 = log_dt[tid];
    const float ldt1 = log_dt[tid + 512];
    const float av   = A[tid & 255];

    const float* xp = x + (size_t)(row0 + rhalf*16 + lr)*HID + kq*256 + hi*8;
    const float* bp = B + (size_t)lr*HID + kq*256 + hi*8;
    float4 xa[8][2], ba[4][2];
    #pragma unroll
    for (int i = 0; i < 8; ++i) {
        xa[i][0] = *(const float4*)(xp + i*32);
        xa[i][1] = *(const float4*)(xp + i*32 + 4);
    }
    #pragma unroll
    for (int i = 0; i < 4; ++i) {
        ba[i][0] = *(const float4*)(bp + i*32);
        ba[i][1] = *(const float4*)(bp + i*32 + 4);
    }
    __builtin_amdgcn_sched_barrier(0);

    // ---- dt = mean(exp(log_dt)): wave reduce + 1 LDS round ----
    float s = expf(ldt0) + expf(ldt1);
    #pragma unroll
    for (int off = 32; off > 0; off >>= 1) s += __shfl_xor(s, off);
    if (lane == 0) red[w] = s;
    LDS_BAR();
    const float dt = (red[0]+red[1]+red[2]+red[3]+red[4]+red[5]+red[6]+red[7])
                     * (1.f/1024.f);

    // ---- Taylor-8 DIRECT on M = A*dt: E = expm, G = phi1 ----
    float* Ms = red + 512; float* t0 = red + 768; float* t1 = red + 1024;
    float* E  = red + 1280; float* G = red + 1536;
    if (tid < 256) {
        Ms[tid] = av * dt;
        t0[tid] = ident; E[tid] = ident; G[tid] = ident;
    }
    LDS_BAR();
    {
        float* tc = t0; float* tn = t1;
        for (int i = 1; i <= 8; ++i) {
            if (tid < 256) {
                float v = 0.f;
                #pragma unroll
                for (int m = 0; m < NS; ++m) v += tc[r16*16+m] * Ms[m*16+c16];
                v /= (float)i;
                tn[tid] = v;
                E[tid] += v;
                G[tid] += v * (1.f/(float)(i+1));
            }
            LDS_BAR();
            float* tt = tc; tc = tn; tn = tt;
        }
    }
    if (tid < 256) {
        Adl[tid] = E[tid];
        Xl[tid]  = dt * G[tid];
    }
    LDS_BAR();

    // ---- table chains (blocks 0..159) run UNDER the x stream; store deferred ----
    float tval = ident;
    if (bid < 160) {
        float* S2 = tbl;            // 6 x 256: A_d^(2^j)
        float* T2 = tbl + 1536;     // 7 x 256: (A_d^32)^(2^j)
        float* V0 = tbl + 3328;
        float* V1 = tbl + 3584;
        if (tid < 256) S2[tid] = Adl[tid];
        LDS_BAR();
        for (int j = 1; j < 6; ++j) {
            float v = 0.f;
            if (tid < 256) {
                #pragma unroll
                for (int m = 0; m < NS; ++m)
                    v += S2[(j-1)*256 + r16*16+m] * S2[(j-1)*256 + m*16+c16];
            }
            LDS_BAR();
            if (tid < 256) S2[j*256 + tid] = v;
            LDS_BAR();
        }
        if (tid < 256) T2[tid] = S2[5*256 + tid];
        LDS_BAR();
        for (int j = 1; j < 7; ++j) {
            float v = 0.f;
            if (tid < 256) {
                #pragma unroll
                for (int m = 0; m < NS; ++m)
                    v += T2[(j-1)*256 + r16*16+m] * T2[(j-1)*256 + m*16+c16];
            }
            LDS_BAR();
            if (tid < 256) T2[j*256 + tid] = v;
            LDS_BAR();
        }
        const bool isP = (bid < 32);
        const int  key = isP ? (bid + 1) : (bid - 32);   // P: 1..32, Q: 0..127
        const float* CH = isP ? S2 : T2;
        const int nbits = isP ? 6 : 7;
        float* Vc = V0; float* Vn = V1;
        bool have = false;
        for (int bit = 0; bit < nbits; ++bit) {
            if (!((key >> bit) & 1)) continue;
            if (!have) {
                if (tid < 256) Vc[tid] = CH[bit*256 + tid];
                have = true;
                LDS_BAR();
            } else {
                float v = 0.f;
                if (tid < 256) {
                    #pragma unroll
                    for (int m = 0; m < NS; ++m)
                        v += Vc[r16*16+m] * CH[bit*256 + m*16+c16];
                }
                LDS_BAR();
                if (tid < 256) Vn[tid] = v;
                LDS_BAR();
                float* tt = Vc; Vc = Vn; Vn = tt;
            }
        }
        if (tid < 256 && have) tval = Vc[tid];
    }

    // ---- MFMA shot A (x/B prefetched), then shot B (B from L2) ----
    f32x4 acc = {0.f, 0.f, 0.f, 0.f};
    #pragma unroll
    for (int i = 0; i < 4; ++i) {
        v8bf a, b;
        a[0]=(__bf16)xa[i][0].x; a[1]=(__bf16)xa[i][0].y; a[2]=(__bf16)xa[i][0].z; a[3]=(__bf16)xa[i][0].w;
        a[4]=(__bf16)xa[i][1].x; a[5]=(__bf16)xa[i][1].y; a[6]=(__bf16)xa[i][1].z; a[7]=(__bf16)xa[i][1].w;
        b[0]=(__bf16)ba[i][0].x; b[1]=(__bf16)ba[i][0].y; b[2]=(__bf16)ba[i][0].z; b[3]=(__bf16)ba[i][0].w;
        b[4]=(__bf16)ba[i][1].x; b[5]=(__bf16)ba[i][1].y; b[6]=(__bf16)ba[i][1].z; b[7]=(__bf16)ba[i][1].w;
        acc = __builtin_amdgcn_mfma_f32_16x16x32_bf16(a, b, acc, 0, 0, 0);
    }
    #pragma unroll
    for (int i = 0; i < 4; ++i) {
        ba[i][0] = *(const float4*)(bp + 128 + i*32);
        ba[i][1] = *(const float4*)(bp + 128 + i*32 + 4);
    }
    #pragma unroll
    for (int i = 0; i < 4; ++i) {
        v8bf a, b;
        a[0]=(__bf16)xa[i+4][0].x; a[1]=(__bf16)xa[i+4][0].y; a[2]=(__bf16)xa[i+4][0].z; a[3]=(__bf16)xa[i+4][0].w;
        a[4]=(__bf16)xa[i+4][1].x; a[5]=(__bf16)xa[i+4][1].y; a[6]=(__bf16)xa[i+4][1].z; a[7]=(__bf16)xa[i+4][1].w;
        b[0]=(__bf16)ba[i][0].x; b[1]=(__bf16)ba[i][0].y; b[2]=(__bf16)ba[i][0].z; b[3]=(__bf16)ba[i][0].w;
        b[4]=(__bf16)ba[i][1].x; b[5]=(__bf16)ba[i][1].y; b[6]=(__bf16)ba[i][1].z; b[7]=(__bf16)ba[i][1].w;
        acc = __builtin_amdgcn_mfma_f32_16x16x32_bf16(a, b, acc, 0, 0, 0);
    }

    // ---- stash per-wave tiles, combine k-slices -> y ----
    #pragma unroll
    for (int rreg = 0; rreg < 4; ++rreg)
        red[w*256 + (hi*4 + rreg)*16 + lr] = acc[rreg];
    __syncthreads();
    {
        const int rowl = tid >> 4, n = tid & 15;
        const int rh = rowl >> 4, rl = rowl & 15;
        float v = 0.f;
        #pragma unroll
        for (int kk = 0; kk < 4; ++kk)
            v += red[(rh + 2*kk)*256 + rl*16 + n];
        usy[tid] = v;
    }
    __syncthreads();
    // ---- X-transform: u[row][n] = sum_m y[row][m] * X[n][m] ----
    {
        const int rowl = tid >> 4, n = tid & 15;
        float v = 0.f;
        #pragma unroll
        for (int m = 0; m < NS; ++m) v += usy[rowl*16 + m] * Xl[n*16 + m];
        us[tid] = v;
    }
    __syncthreads();
    // ---- local scan over 32 steps (wave 0, m-split 4-way) ----
    if (tid < 64) {
        const int n = tid & 15, mg = tid >> 4;
        const float a0 = Adl[(mg*4+0)*16 + n];
        const float a1 = Adl[(mg*4+1)*16 + n];
        const float a2 = Adl[(mg*4+2)*16 + n];
        const float a3 = Adl[(mg*4+3)*16 + n];
        float v = 0.f;
        for (int t = 0; t < CHUNK; ++t) {
            const float u0 = us[t*16 + n];
            float q = __shfl(v, mg*4+0, 16)*a0 + __shfl(v, mg*4+1, 16)*a1
                    + __shfl(v, mg*4+2, 16)*a2 + __shfl(v, mg*4+3, 16)*a3;
            q += __shfl_xor(q, 16);
            q += __shfl_xor(q, 32);
            v = u0 + q;
            if (mg == 0) us[t*16 + n] = v;
        }
        if (mg == 0) {
            const int b = row0 >> 12, cch = (row0 >> 5) & (NCH-1);
            ws[OFF_LEND + (b*NCH + cch)*16 + n] = v;
        }
    }
    __syncthreads();
    if (tid < 128) {
        const int j = tid >> 2, nq = (tid & 3)*4;
        *(float4*)(ws + OFF_U + (size_t)(row0 + j)*16 + nq) = *(const float4*)(&us[j*16 + nq]);
    }

    // ---- deferred table store ----
    if (bid < 160 && tid < 256) {
        if (bid < 32) ws[OFF_P + (bid+1-1)*256 + tid] = tval;
        else          ws[OFF_Q + (bid-32)*256 + tid]  = tval;
    }
}

// ---------- K2: cin via Q-table sum (32 groups), correction, out-GEMM ----------
// (round-11/15/17/19 proven, unchanged)
__global__ __launch_bounds__(512, 4) void k2_kernel(const float* __restrict__ C,
                                                    const float* __restrict__ state,
                                                    const float* __restrict__ ws,
                                                    float* __restrict__ out) {
    __shared__ __align__(16) float st[32*20];     // padded stride 20
    __shared__ float vec[(NCH+1)*16];             // lend_0..c-1, state0
    __shared__ float part[32*17];
    __shared__ float cin_s[16];
    const int tid = threadIdx.x;
    const int row0 = blockIdx.x * 32;
    const int b = row0 >> 12, cch = (row0 >> 5) & (NCH-1);

    if (tid < 128) {
        const int j = tid >> 2, n4 = (tid & 3)*4;
        *(float4*)(&st[j*20 + n4]) =
            *(const float4*)(ws + OFF_U + (size_t)(row0 + j)*16 + n4);
    }
    for (int i = tid; i < cch*16; i += 512)
        vec[i] = ws[OFF_LEND + b*NCH*16 + i];
    if (tid < 16) vec[cch*16 + tid] = state[b*16 + tid];
    __syncthreads();

    {
        const int g = tid >> 4, n2 = tid & 15;
        float p = 0.f;
        for (int j = g; j <= cch; j += 32) {
            const int qidx = (j == cch) ? cch : (cch - 1 - j);
            const float* Q = ws + OFF_Q + qidx*256;
            float sv = 0.f;
            #pragma unroll
            for (int m = 0; m < NS; ++m) sv += vec[j*16 + m] * Q[m*16 + n2];
            p += sv;
        }
        part[g*17 + n2] = p;
    }
    __syncthreads();
    for (int s2 = 16; s2 > 0; s2 >>= 1) {
        if ((tid >> 4) < s2)
            part[(tid>>4)*17 + (tid&15)] += part[((tid>>4)+s2)*17 + (tid&15)];
        __syncthreads();
    }
    if (tid < 16) cin_s[tid] = part[tid];
    __syncthreads();

    if (tid < 128) {
        const int j = tid >> 2, n4 = (tid & 3)*4;
        float4 ls = *(const float4*)(&st[j*20 + n4]);
        const float* P = ws + OFF_P + j*256 + n4;
        float cx=0.f, cy=0.f, cz=0.f, cw=0.f;
        #pragma unroll
        for (int m = 0; m < NS; ++m) {
            const float cm = cin_s[m];
            float4 pv = *(const float4*)(P + m*16);
            cx += cm*pv.x; cy += cm*pv.y; cz += cm*pv.z; cw += cm*pv.w;
        }
        *(float4*)(&st[j*20 + n4]) = make_float4(ls.x+cx, ls.y+cy, ls.z+cz, ls.w+cw);
    }
    __syncthreads();
    if (cch == NCH-1 && tid < 16)
        out[(size_t)ROWS*HID + b*16 + tid] = st[31*20 + tid];

    const int w = tid >> 6, lane = tid & 63;
    const int rhalf = w & 1, cg = w >> 1;
    const int lr = lane & 15;
    const int hi = lane >> 4;
    const int lk = hi * 8;

    v8bf afr = {};
    if (lk < 16) {
        float4 s0 = *(const float4*)(&st[(rhalf*16 + lr)*20 + lk]);
        float4 s1 = *(const float4*)(&st[(rhalf*16 + lr)*20 + lk + 4]);
        afr[0]=(__bf16)s0.x; afr[1]=(__bf16)s0.y; afr[2]=(__bf16)s0.z; afr[3]=(__bf16)s0.w;
        afr[4]=(__bf16)s1.x; afr[5]=(__bf16)s1.y; afr[6]=(__bf16)s1.z; afr[7]=(__bf16)s1.w;
    }
    const int orow = row0 + rhalf*16 + hi*4;

    float4 pc0, pc1;
    {
        const int n0 = (cg*16)*16;
        if (lk < 16) {
            pc0 = *(const float4*)(C + (size_t)(n0 + lr)*16 + lk);
            pc1 = *(const float4*)(C + (size_t)(n0 + lr)*16 + lk + 4);
        }
    }
    #pragma unroll 4
    for (int nt = 0; nt < 16; ++nt) {
        const int n0 = (cg*16 + nt)*16;
        float4 c0 = pc0, c1 = pc1;
        if (nt + 1 < 16 && lk < 16) {
            const int n1 = (cg*16 + nt + 1)*16;
            pc0 = *(const float4*)(C + (size_t)(n1 + lr)*16 + lk);
            pc1 = *(const float4*)(C + (size_t)(n1 + lr)*16 + lk + 4);
        }
        v8bf bfr = {};
        if (lk < 16) {
            bfr[0]=(__bf16)c0.x; bfr[1]=(__bf16)c0.y; bfr[2]=(__bf16)c0.z; bfr[3]=(__bf16)c0.w;
            bfr[4]=(__bf16)c1.x; bfr[5]=(__bf16)c1.y; bfr[6]=(__bf16)c1.z; bfr[7]=(__bf16)c1.w;
        }
        f32x4 acc2 = {0.f, 0.f, 0.f, 0.f};
        acc2 = __builtin_amdgcn_mfma_f32_16x16x32_bf16(afr, bfr, acc2, 0, 0, 0);
        #pragma unroll
        for (int rg = 0; rg < 4; ++rg)
            out[(size_t)(orow + rg)*HID + n0 + lr] = acc2[rg];
    }
}

extern "C" void kernel_launch(void* const* d_in, const int* in_sizes, int n_in,
                              void* d_out, int out_size, void* d_ws, size_t ws_size,
                              hipStream_t stream) {
    (void)in_sizes; (void)n_in; (void)out_size; (void)ws_size;
    const float* x      = (const float*)d_in[0];
    const float* state  = (const float*)d_in[1];
    const float* A      = (const float*)d_in[2];
    const float* B      = (const float*)d_in[3];
    const float* C      = (const float*)d_in[4];
    const float* log_dt = (const float*)d_in[5];
    float* out = (float*)d_out;
    float* ws  = (float*)d_ws;

    k1_fused<<<ROWS/32, 512, 0, stream>>>(x, A, B, log_dt, ws);
    k2_kernel<<<ROWS/32, 512, 0, stream>>>(C, state, ws, out);
}

// Round 22
// 45.860 us; speedup vs baseline: 1.0439x; 1.0439x over previous
//
#include <hip/hip_runtime.h>
#include <cstddef>

#define T_LEN 4096
#define BATCH 4
#define HID   1024
#define NS    16
#define ROWS  (BATCH*T_LEN)   // 16384
#define CHUNK 32
#define NCH   (T_LEN/CHUNK)   // 128

// workspace float offsets
#define OFF_P    1024     // P_j = A_d^(j+1), j=0..31   [32][16][16]
#define OFF_Q    32768    // Q_k = (A_d^32)^k, k=0..127 [128][16][16]
#define OFF_U    65536    // local states [16384][16]
#define OFF_LEND 327680   // chunk-end local states [4][128][16]

typedef __bf16 v8bf  __attribute__((ext_vector_type(8)));
typedef float  f32x4 __attribute__((ext_vector_type(4)));

// LDS-only barrier: does NOT drain vmcnt -> global loads stay in flight.
#define LDS_BAR() do { \
    __builtin_amdgcn_sched_barrier(0); \
    asm volatile("s_waitcnt lgkmcnt(0)" ::: "memory"); \
    __builtin_amdgcn_s_barrier(); \
    __builtin_amdgcn_sched_barrier(0); } while (0)

// ---------- K1 fused: shot-A prefetch, setup (Taylor-8) + table chains run
//            UNDER the x stream (lgkmcnt-only barriers), then streaming
//            y = x @ B^T, X-transform + scan; blocks 0..159 emit one P/Q
//            entry (global store deferred to kernel end) ----------
__global__ __launch_bounds__(512, 4) void k1_fused(const float* __restrict__ x,
                                                   const float* __restrict__ A,
                                                   const float* __restrict__ B,
                                                   const float* __restrict__ log_dt,
                                                   float* __restrict__ ws) {
    __shared__ __align__(16) float red[2048];      // setup scratch -> MFMA tiles (8KB)
    __shared__ __align__(16) float usy[512];       // y values
    __shared__ __align__(16) float us[512];        // u -> local states
    __shared__ float Adl[256], Xl[256];            // 2KB persistent
    __shared__ __align__(16) float tbl[3840];      // table scratch (15KB)
    const int tid  = threadIdx.x;
    const int w    = tid >> 6;
    const int lane = tid & 63;
    const int bid  = blockIdx.x;
    const int row0 = bid * 32;
    const int rhalf = w & 1;           // 16-row half
    const int kq    = w >> 1;          // 256-wide K slice
    const int lr = lane & 15;
    const int hi = lane >> 4;
    const int r16 = (tid >> 4) & 15, c16 = tid & 15;
    const float ident = (r16 == c16) ? 1.f : 0.f;

    // ---- prefetch: setup scalars first, then shot-A x/B (stays in flight) ----
    const float ldt0 = log_dt[tid];
    const float ldt1 = log_dt[tid + 512];
    const float av   = A[tid & 255];

    const float* xp = x + (size_t)(row0 + rhalf*16 + lr)*HID + kq*256 + hi*8;
    const float* bp = B + (size_t)lr*HID + kq*256 + hi*8;
    float4 xa[4][2], ba[4][2];
    #pragma unroll
    for (int i = 0; i < 4; ++i) {
        xa[i][0] = *(const float4*)(xp + i*32);
        xa[i][1] = *(const float4*)(xp + i*32 + 4);
        ba[i][0] = *(const float4*)(bp + i*32);
        ba[i][1] = *(const float4*)(bp + i*32 + 4);
    }
    __builtin_amdgcn_sched_barrier(0);

    // ---- dt = mean(exp(log_dt)): wave reduce + 1 LDS round ----
    float s = expf(ldt0) + expf(ldt1);
    #pragma unroll
    for (int off = 32; off > 0; off >>= 1) s += __shfl_xor(s, off);
    if (lane == 0) red[w] = s;
    LDS_BAR();
    const float dt = (red[0]+red[1]+red[2]+red[3]+red[4]+red[5]+red[6]+red[7])
                     * (1.f/1024.f);

    // ---- Taylor-8 DIRECT on M = A*dt: E = expm, G = phi1 ----
    float* Ms = red + 512; float* t0 = red + 768; float* t1 = red + 1024;
    float* E  = red + 1280; float* G = red + 1536;
    if (tid < 256) {
        Ms[tid] = av * dt;
        t0[tid] = ident; E[tid] = ident; G[tid] = ident;
    }
    LDS_BAR();
    {
        float* tc = t0; float* tn = t1;
        for (int i = 1; i <= 8; ++i) {
            if (tid < 256) {
                float v = 0.f;
                #pragma unroll
                for (int m = 0; m < NS; ++m) v += tc[r16*16+m] * Ms[m*16+c16];
                v /= (float)i;
                tn[tid] = v;
                E[tid] += v;
                G[tid] += v * (1.f/(float)(i+1));
            }
            LDS_BAR();
            float* tt = tc; tc = tn; tn = tt;
        }
    }
    if (tid < 256) {
        Adl[tid] = E[tid];
        Xl[tid]  = dt * G[tid];
    }
    LDS_BAR();

    // ---- table chains (blocks 0..159) run UNDER the x stream ----
    float tval = ident;
    if (bid < 160) {
        float* S2 = tbl;            // 6 x 256: A_d^(2^j)
        float* T2 = tbl + 1536;     // 7 x 256: (A_d^32)^(2^j)
        float* V0 = tbl + 3328;
        float* V1 = tbl + 3584;
        if (tid < 256) S2[tid] = Adl[tid];
        LDS_BAR();
        for (int j = 1; j < 6; ++j) {
            float v = 0.f;
            if (tid < 256) {
                #pragma unroll
                for (int m = 0; m < NS; ++m)
                    v += S2[(j-1)*256 + r16*16+m] * S2[(j-1)*256 + m*16+c16];
            }
            LDS_BAR();
            if (tid < 256) S2[j*256 + tid] = v;
            LDS_BAR();
        }
        if (tid < 256) T2[tid] = S2[5*256 + tid];
        LDS_BAR();
        for (int j = 1; j < 7; ++j) {
            float v = 0.f;
            if (tid < 256) {
                #pragma unroll
                for (int m = 0; m < NS; ++m)
                    v += T2[(j-1)*256 + r16*16+m] * T2[(j-1)*256 + m*16+c16];
            }
            LDS_BAR();
            if (tid < 256) T2[j*256 + tid] = v;
            LDS_BAR();
        }
        const bool isP = (bid < 32);
        const int  key = isP ? (bid + 1) : (bid - 32);   // P: 1..32, Q: 0..127
        const float* CH = isP ? S2 : T2;
        const int nbits = isP ? 6 : 7;
        float* Vc = V0; float* Vn = V1;
        bool have = false;
        for (int bit = 0; bit < nbits; ++bit) {
            if (!((key >> bit) & 1)) continue;
            if (!have) {
                if (tid < 256) Vc[tid] = CH[bit*256 + tid];
                have = true;
                LDS_BAR();
            } else {
                float v = 0.f;
                if (tid < 256) {
                    #pragma unroll
                    for (int m = 0; m < NS; ++m)
                        v += Vc[r16*16+m] * CH[bit*256 + m*16+c16];
                }
                LDS_BAR();
                if (tid < 256) Vn[tid] = v;
                LDS_BAR();
                float* tt = Vc; Vc = Vn; Vn = tt;
            }
        }
        if (tid < 256 && have) tval = Vc[tid];
    }

    // ---- MFMA shot A (prefetched), then shot B (loads between shots) ----
    f32x4 acc = {0.f, 0.f, 0.f, 0.f};
    #pragma unroll
    for (int i = 0; i < 4; ++i) {
        v8bf a, b;
        a[0]=(__bf16)xa[i][0].x; a[1]=(__bf16)xa[i][0].y; a[2]=(__bf16)xa[i][0].z; a[3]=(__bf16)xa[i][0].w;
        a[4]=(__bf16)xa[i][1].x; a[5]=(__bf16)xa[i][1].y; a[6]=(__bf16)xa[i][1].z; a[7]=(__bf16)xa[i][1].w;
        b[0]=(__bf16)ba[i][0].x; b[1]=(__bf16)ba[i][0].y; b[2]=(__bf16)ba[i][0].z; b[3]=(__bf16)ba[i][0].w;
        b[4]=(__bf16)ba[i][1].x; b[5]=(__bf16)ba[i][1].y; b[6]=(__bf16)ba[i][1].z; b[7]=(__bf16)ba[i][1].w;
        acc = __builtin_amdgcn_mfma_f32_16x16x32_bf16(a, b, acc, 0, 0, 0);
    }
    #pragma unroll
    for (int i = 0; i < 4; ++i) {
        xa[i][0] = *(const float4*)(xp + 128 + i*32);
        xa[i][1] = *(const float4*)(xp + 128 + i*32 + 4);
        ba[i][0] = *(const float4*)(bp + 128 + i*32);
        ba[i][1] = *(const float4*)(bp + 128 + i*32 + 4);
    }
    #pragma unroll
    for (int i = 0; i < 4; ++i) {
        v8bf a, b;
        a[0]=(__bf16)xa[i][0].x; a[1]=(__bf16)xa[i][0].y; a[2]=(__bf16)xa[i][0].z; a[3]=(__bf16)xa[i][0].w;
        a[4]=(__bf16)xa[i][1].x; a[5]=(__bf16)xa[i][1].y; a[6]=(__bf16)xa[i][1].z; a[7]=(__bf16)xa[i][1].w;
        b[0]=(__bf16)ba[i][0].x; b[1]=(__bf16)ba[i][0].y; b[2]=(__bf16)ba[i][0].z; b[3]=(__bf16)ba[i][0].w;
        b[4]=(__bf16)ba[i][1].x; b[5]=(__bf16)ba[i][1].y; b[6]=(__bf16)ba[i][1].z; b[7]=(__bf16)ba[i][1].w;
        acc = __builtin_amdgcn_mfma_f32_16x16x32_bf16(a, b, acc, 0, 0, 0);
    }

    // ---- stash per-wave tiles, combine k-slices -> y ----
    #pragma unroll
    for (int rreg = 0; rreg < 4; ++rreg)
        red[w*256 + (hi*4 + rreg)*16 + lr] = acc[rreg];
    __syncthreads();
    {
        const int rowl = tid >> 4, n = tid & 15;
        const int rh = rowl >> 4, rl = rowl & 15;
        float v = 0.f;
        #pragma unroll
        for (int kk = 0; kk < 4; ++kk)
            v += red[(rh + 2*kk)*256 + rl*16 + n];
        usy[tid] = v;
    }
    __syncthreads();
    // ---- X-transform: u[row][n] = sum_m y[row][m] * X[n][m] ----
    {
        const int rowl = tid >> 4, n = tid & 15;
        float v = 0.f;
        #pragma unroll
        for (int m = 0; m < NS; ++m) v += usy[rowl*16 + m] * Xl[n*16 + m];
        us[tid] = v;
    }
    __syncthreads();
    // ---- local scan over 32 steps (wave 0, m-split 4-way) ----
    if (tid < 64) {
        const int n = tid & 15, mg = tid >> 4;
        const float a0 = Adl[(mg*4+0)*16 + n];
        const float a1 = Adl[(mg*4+1)*16 + n];
        const float a2 = Adl[(mg*4+2)*16 + n];
        const float a3 = Adl[(mg*4+3)*16 + n];
        float v = 0.f;
        for (int t = 0; t < CHUNK; ++t) {
            const float u0 = us[t*16 + n];
            float q = __shfl(v, mg*4+0, 16)*a0 + __shfl(v, mg*4+1, 16)*a1
                    + __shfl(v, mg*4+2, 16)*a2 + __shfl(v, mg*4+3, 16)*a3;
            q += __shfl_xor(q, 16);
            q += __shfl_xor(q, 32);
            v = u0 + q;
            if (mg == 0) us[t*16 + n] = v;
        }
        if (mg == 0) {
            const int b = row0 >> 12, cch = (row0 >> 5) & (NCH-1);
            ws[OFF_LEND + (b*NCH + cch)*16 + n] = v;
        }
    }
    __syncthreads();
    if (tid < 128) {
        const int j = tid >> 2, nq = (tid & 3)*4;
        *(float4*)(ws + OFF_U + (size_t)(row0 + j)*16 + nq) = *(const float4*)(&us[j*16 + nq]);
    }

    // ---- deferred table store ----
    if (bid < 160 && tid < 256) {
        if (bid < 32) ws[OFF_P + (bid)*256 + tid] = tval;     // P_{bid+1}
        else          ws[OFF_Q + (bid-32)*256 + tid] = tval;  // Q_{bid-32}
    }
}

// ---------- K2: cin via Q-table sum (32 groups), correction, out-GEMM ----------
// (round-11/15/17/19 proven, unchanged)
__global__ __launch_bounds__(512, 4) void k2_kernel(const float* __restrict__ C,
                                                    const float* __restrict__ state,
                                                    const float* __restrict__ ws,
                                                    float* __restrict__ out) {
    __shared__ __align__(16) float st[32*20];     // padded stride 20
    __shared__ float vec[(NCH+1)*16];             // lend_0..c-1, state0
    __shared__ float part[32*17];
    __shared__ float cin_s[16];
    const int tid = threadIdx.x;
    const int row0 = blockIdx.x * 32;
    const int b = row0 >> 12, cch = (row0 >> 5) & (NCH-1);

    if (tid < 128) {
        const int j = tid >> 2, n4 = (tid & 3)*4;
        *(float4*)(&st[j*20 + n4]) =
            *(const float4*)(ws + OFF_U + (size_t)(row0 + j)*16 + n4);
    }
    for (int i = tid; i < cch*16; i += 512)
        vec[i] = ws[OFF_LEND + b*NCH*16 + i];
    if (tid < 16) vec[cch*16 + tid] = state[b*16 + tid];
    __syncthreads();

    {
        const int g = tid >> 4, n2 = tid & 15;
        float p = 0.f;
        for (int j = g; j <= cch; j += 32) {
            const int qidx = (j == cch) ? cch : (cch - 1 - j);
            const float* Q = ws + OFF_Q + qidx*256;
            float sv = 0.f;
            #pragma unroll
            for (int m = 0; m < NS; ++m) sv += vec[j*16 + m] * Q[m*16 + n2];
            p += sv;
        }
        part[g*17 + n2] = p;
    }
    __syncthreads();
    for (int s2 = 16; s2 > 0; s2 >>= 1) {
        if ((tid >> 4) < s2)
            part[(tid>>4)*17 + (tid&15)] += part[((tid>>4)+s2)*17 + (tid&15)];
        __syncthreads();
    }
    if (tid < 16) cin_s[tid] = part[tid];
    __syncthreads();

    if (tid < 128) {
        const int j = tid >> 2, n4 = (tid & 3)*4;
        float4 ls = *(const float4*)(&st[j*20 + n4]);
        const float* P = ws + OFF_P + j*256 + n4;
        float cx=0.f, cy=0.f, cz=0.f, cw=0.f;
        #pragma unroll
        for (int m = 0; m < NS; ++m) {
            const float cm = cin_s[m];
            float4 pv = *(const float4*)(P + m*16);
            cx += cm*pv.x; cy += cm*pv.y; cz += cm*pv.z; cw += cm*pv.w;
        }
        *(float4*)(&st[j*20 + n4]) = make_float4(ls.x+cx, ls.y+cy, ls.z+cz, ls.w+cw);
    }
    __syncthreads();
    if (cch == NCH-1 && tid < 16)
        out[(size_t)ROWS*HID + b*16 + tid] = st[31*20 + tid];

    const int w = tid >> 6, lane = tid & 63;
    const int rhalf = w & 1, cg = w >> 1;
    const int lr = lane & 15;
    const int hi = lane >> 4;
    const int lk = hi * 8;

    v8bf afr = {};
    if (lk < 16) {
        float4 s0 = *(const float4*)(&st[(rhalf*16 + lr)*20 + lk]);
        float4 s1 = *(const float4*)(&st[(rhalf*16 + lr)*20 + lk + 4]);
        afr[0]=(__bf16)s0.x; afr[1]=(__bf16)s0.y; afr[2]=(__bf16)s0.z; afr[3]=(__bf16)s0.w;
        afr[4]=(__bf16)s1.x; afr[5]=(__bf16)s1.y; afr[6]=(__bf16)s1.z; afr[7]=(__bf16)s1.w;
    }
    const int orow = row0 + rhalf*16 + hi*4;

    float4 pc0, pc1;
    {
        const int n0 = (cg*16)*16;
        if (lk < 16) {
            pc0 = *(const float4*)(C + (size_t)(n0 + lr)*16 + lk);
            pc1 = *(const float4*)(C + (size_t)(n0 + lr)*16 + lk + 4);
        }
    }
    #pragma unroll 4
    for (int nt = 0; nt < 16; ++nt) {
        const int n0 = (cg*16 + nt)*16;
        float4 c0 = pc0, c1 = pc1;
        if (nt + 1 < 16 && lk < 16) {
            const int n1 = (cg*16 + nt + 1)*16;
            pc0 = *(const float4*)(C + (size_t)(n1 + lr)*16 + lk);
            pc1 = *(const float4*)(C + (size_t)(n1 + lr)*16 + lk + 4);
        }
        v8bf bfr = {};
        if (lk < 16) {
            bfr[0]=(__bf16)c0.x; bfr[1]=(__bf16)c0.y; bfr[2]=(__bf16)c0.z; bfr[3]=(__bf16)c0.w;
            bfr[4]=(__bf16)c1.x; bfr[5]=(__bf16)c1.y; bfr[6]=(__bf16)c1.z; bfr[7]=(__bf16)c1.w;
        }
        f32x4 acc2 = {0.f, 0.f, 0.f, 0.f};
        acc2 = __builtin_amdgcn_mfma_f32_16x16x32_bf16(afr, bfr, acc2, 0, 0, 0);
        #pragma unroll
        for (int rg = 0; rg < 4; ++rg)
            out[(size_t)(orow + rg)*HID + n0 + lr] = acc2[rg];
    }
}

extern "C" void kernel_launch(void* const* d_in, const int* in_sizes, int n_in,
                              void* d_out, int out_size, void* d_ws, size_t ws_size,
                              hipStream_t stream) {
    (void)in_sizes; (void)n_in; (void)out_size; (void)ws_size;
    const float* x      = (const float*)d_in[0];
    const float* state  = (const float*)d_in[1];
    const float* A      = (const float*)d_in[2];
    const float* B      = (const float*)d_in[3];
    const float* C      = (const float*)d_in[4];
    const float* log_dt = (const float*)d_in[5];
    float* out = (float*)d_out;
    float* ws  = (float*)d_ws;

    k1_fused<<<ROWS/32, 512, 0, stream>>>(x, A, B, log_dt, ws);
    k2_kernel<<<ROWS/32, 512, 0, stream>>>(C, state, ws, out);
}

// Round 23
// 43.183 us; speedup vs baseline: 1.1086x; 1.0620x over previous
//
#include <hip/hip_runtime.h>
#include <cstddef>

#define T_LEN 4096
#define BATCH 4
#define HID   1024
#define NS    16
#define ROWS  (BATCH*T_LEN)   // 16384
#define CHUNK 32
#define NCH   (T_LEN/CHUNK)   // 128

// workspace float offsets
#define OFF_P    1024     // P_j = A_d^(j+1), j=0..31   [32][16][16]
#define OFF_Q    32768    // Q_k = (A_d^32)^k, k=0..127 [128][16][16]
#define OFF_U    65536    // local states [16384][16]
#define OFF_LEND 327680   // chunk-end local states [4][128][16]

typedef __bf16 v8bf  __attribute__((ext_vector_type(8)));
typedef float  f32x4 __attribute__((ext_vector_type(4)));

// LDS-only barrier: does NOT drain vmcnt -> global loads stay in flight.
#define LDS_BAR() do { \
    __builtin_amdgcn_sched_barrier(0); \
    asm volatile("s_waitcnt lgkmcnt(0)" ::: "memory"); \
    __builtin_amdgcn_s_barrier(); \
    __builtin_amdgcn_sched_barrier(0); } while (0)

// ---------- K1 fused: prefetch x/B shot-A, setup (Taylor-8 direct) overlapped
//            with the stream via lgkmcnt-only barriers, streaming y = x @ B^T,
//            X-transform + scan fused; blocks 0..159 emit one P/Q entry ----------
__global__ __launch_bounds__(512, 4) void k1_fused(const float* __restrict__ x,
                                                   const float* __restrict__ A,
                                                   const float* __restrict__ B,
                                                   const float* __restrict__ log_dt,
                                                   float* __restrict__ ws) {
    __shared__ __align__(16) float red[2048];      // setup scratch -> MFMA tiles (8KB)
    __shared__ __align__(16) float usy[512];       // y values
    __shared__ __align__(16) float us[512];        // u -> local states
    __shared__ float Adl[256], Xl[256], Esv[256];  // 3KB persistent
    __shared__ __align__(16) float tbl[3840];      // table scratch (15KB)
    const int tid  = threadIdx.x;
    const int w    = tid >> 6;
    const int lane = tid & 63;
    const int bid  = blockIdx.x;
    const int row0 = bid * 32;
    const int rhalf = w & 1;           // 16-row half
    const int kq    = w >> 1;          // 256-wide K slice
    const int lr = lane & 15;
    const int hi = lane >> 4;
    const int r16 = (tid >> 4) & 15, c16 = tid & 15;
    const float ident = (r16 == c16) ? 1.f : 0.f;

    // ---- prefetch: setup scalars first, then shot-A x/B (stays in flight) ----
    const float ldt0 = log_dt[tid];
    const float ldt1 = log_dt[tid + 512];
    const float av   = A[tid & 255];

    const float* xp = x + (size_t)(row0 + rhalf*16 + lr)*HID + kq*256 + hi*8;
    const float* bp = B + (size_t)lr*HID + kq*256 + hi*8;
    float4 xa[4][2], ba[4][2];
    #pragma unroll
    for (int i = 0; i < 4; ++i) {
        xa[i][0] = *(const float4*)(xp + i*32);
        xa[i][1] = *(const float4*)(xp + i*32 + 4);
        ba[i][0] = *(const float4*)(bp + i*32);
        ba[i][1] = *(const float4*)(bp + i*32 + 4);
    }
    __builtin_amdgcn_sched_barrier(0);

    // ---- dt = mean(exp(log_dt)): wave reduce + 1 LDS round ----
    float s = expf(ldt0) + expf(ldt1);
    #pragma unroll
    for (int off = 32; off > 0; off >>= 1) s += __shfl_xor(s, off);
    if (lane == 0) red[w] = s;
    LDS_BAR();
    const float dt = (red[0]+red[1]+red[2]+red[3]+red[4]+red[5]+red[6]+red[7])
                     * (1.f/1024.f);

    // ---- Taylor-8 DIRECT on M = A*dt (||M||~2e-3: no squaring needed).
    //      E = expm(M);  G = phi1(M) = sum term_i/(i+1) ----
    float* Ms = red + 512; float* t0 = red + 768; float* t1 = red + 1024;
    float* E  = red + 1280; float* G = red + 1536;
    if (tid < 256) {
        Ms[tid] = av * dt;
        t0[tid] = ident; E[tid] = ident; G[tid] = ident;
    }
    LDS_BAR();
    {
        float* tc = t0; float* tn = t1;
        for (int i = 1; i <= 8; ++i) {
            if (tid < 256) {
                float v = 0.f;
                #pragma unroll
                for (int m = 0; m < NS; ++m) v += tc[r16*16+m] * Ms[m*16+c16];
                v /= (float)i;
                tn[tid] = v;
                E[tid] += v;
                G[tid] += v * (1.f/(float)(i+1));
            }
            LDS_BAR();
            float* tt = tc; tc = tn; tn = tt;
        }
    }
    if (tid < 256) {
        Adl[tid] = E[tid];
        Xl[tid]  = dt * G[tid];
        Esv[tid] = E[tid];
    }
    LDS_BAR();   // red now free for MFMA tiles

    // ---- MFMA shot A (K 0..127 of slice), then shot B (128..255) ----
    f32x4 acc = {0.f, 0.f, 0.f, 0.f};
    #pragma unroll
    for (int i = 0; i < 4; ++i) {
        v8bf a, b;
        a[0]=(__bf16)xa[i][0].x; a[1]=(__bf16)xa[i][0].y; a[2]=(__bf16)xa[i][0].z; a[3]=(__bf16)xa[i][0].w;
        a[4]=(__bf16)xa[i][1].x; a[5]=(__bf16)xa[i][1].y; a[6]=(__bf16)xa[i][1].z; a[7]=(__bf16)xa[i][1].w;
        b[0]=(__bf16)ba[i][0].x; b[1]=(__bf16)ba[i][0].y; b[2]=(__bf16)ba[i][0].z; b[3]=(__bf16)ba[i][0].w;
        b[4]=(__bf16)ba[i][1].x; b[5]=(__bf16)ba[i][1].y; b[6]=(__bf16)ba[i][1].z; b[7]=(__bf16)ba[i][1].w;
        acc = __builtin_amdgcn_mfma_f32_16x16x32_bf16(a, b, acc, 0, 0, 0);
    }
    #pragma unroll
    for (int i = 0; i < 4; ++i) {
        xa[i][0] = *(const float4*)(xp + 128 + i*32);
        xa[i][1] = *(const float4*)(xp + 128 + i*32 + 4);
        ba[i][0] = *(const float4*)(bp + 128 + i*32);
        ba[i][1] = *(const float4*)(bp + 128 + i*32 + 4);
    }
    #pragma unroll
    for (int i = 0; i < 4; ++i) {
        v8bf a, b;
        a[0]=(__bf16)xa[i][0].x; a[1]=(__bf16)xa[i][0].y; a[2]=(__bf16)xa[i][0].z; a[3]=(__bf16)xa[i][0].w;
        a[4]=(__bf16)xa[i][1].x; a[5]=(__bf16)xa[i][1].y; a[6]=(__bf16)xa[i][1].z; a[7]=(__bf16)xa[i][1].w;
        b[0]=(__bf16)ba[i][0].x; b[1]=(__bf16)ba[i][0].y; b[2]=(__bf16)ba[i][0].z; b[3]=(__bf16)ba[i][0].w;
        b[4]=(__bf16)ba[i][1].x; b[5]=(__bf16)ba[i][1].y; b[6]=(__bf16)ba[i][1].z; b[7]=(__bf16)ba[i][1].w;
        acc = __builtin_amdgcn_mfma_f32_16x16x32_bf16(a, b, acc, 0, 0, 0);
    }

    // ---- stash per-wave tiles, combine k-slices -> y ----
    #pragma unroll
    for (int rreg = 0; rreg < 4; ++rreg)
        red[w*256 + (hi*4 + rreg)*16 + lr] = acc[rreg];
    __syncthreads();
    {
        const int rowl = tid >> 4, n = tid & 15;
        const int rh = rowl >> 4, rl = rowl & 15;
        float v = 0.f;
        #pragma unroll
        for (int kk = 0; kk < 4; ++kk)
            v += red[(rh + 2*kk)*256 + rl*16 + n];
        usy[tid] = v;
    }
    __syncthreads();
    // ---- X-transform: u[row][n] = sum_m y[row][m] * X[n][m] ----
    {
        const int rowl = tid >> 4, n = tid & 15;
        float v = 0.f;
        #pragma unroll
        for (int m = 0; m < NS; ++m) v += usy[rowl*16 + m] * Xl[n*16 + m];
        us[tid] = v;
    }
    __syncthreads();
    // ---- local scan over 32 steps (wave 0, m-split 4-way) ----
    if (tid < 64) {
        const int n = tid & 15, mg = tid >> 4;
        const float a0 = Adl[(mg*4+0)*16 + n];
        const float a1 = Adl[(mg*4+1)*16 + n];
        const float a2 = Adl[(mg*4+2)*16 + n];
        const float a3 = Adl[(mg*4+3)*16 + n];
        float v = 0.f;
        for (int t = 0; t < CHUNK; ++t) {
            const float u0 = us[t*16 + n];
            float q = __shfl(v, mg*4+0, 16)*a0 + __shfl(v, mg*4+1, 16)*a1
                    + __shfl(v, mg*4+2, 16)*a2 + __shfl(v, mg*4+3, 16)*a3;
            q += __shfl_xor(q, 16);
            q += __shfl_xor(q, 32);
            v = u0 + q;
            if (mg == 0) us[t*16 + n] = v;
        }
        if (mg == 0) {
            const int b = row0 >> 12, cch = (row0 >> 5) & (NCH-1);
            ws[OFF_LEND + (b*NCH + cch)*16 + n] = v;
        }
    }
    __syncthreads();
    if (tid < 128) {
        const int j = tid >> 2, nq = (tid & 3)*4;
        *(float4*)(ws + OFF_U + (size_t)(row0 + j)*16 + nq) = *(const float4*)(&us[j*16 + nq]);
    }

    // ---- tables: blocks 0..31 -> P_{bid+1}; 32..159 -> Q_{bid-32} ----
    if (bid < 160) {
        float* S2 = tbl;            // 6 x 256: A_d^(2^j)
        float* T2 = tbl + 1536;     // 7 x 256: (A_d^32)^(2^j)
        float* V0 = tbl + 3328;
        float* V1 = tbl + 3584;
        if (tid < 256) S2[tid] = Esv[tid];
        LDS_BAR();
        for (int j = 1; j < 6; ++j) {
            float v = 0.f;
            if (tid < 256) {
                #pragma unroll
                for (int m = 0; m < NS; ++m)
                    v += S2[(j-1)*256 + r16*16+m] * S2[(j-1)*256 + m*16+c16];
            }
            LDS_BAR();
            if (tid < 256) S2[j*256 + tid] = v;
            LDS_BAR();
        }
        if (tid < 256) T2[tid] = S2[5*256 + tid];
        LDS_BAR();
        for (int j = 1; j < 7; ++j) {
            float v = 0.f;
            if (tid < 256) {
                #pragma unroll
                for (int m = 0; m < NS; ++m)
                    v += T2[(j-1)*256 + r16*16+m] * T2[(j-1)*256 + m*16+c16];
            }
            LDS_BAR();
            if (tid < 256) T2[j*256 + tid] = v;
            LDS_BAR();
        }
        const bool isP = (bid < 32);
        const int  key = isP ? (bid + 1) : (bid - 32);   // P: 1..32, Q: 0..127
        const float* CH = isP ? S2 : T2;
        const int nbits = isP ? 6 : 7;
        float* Vc = V0; float* Vn = V1;
        bool have = false;
        for (int bit = 0; bit < nbits; ++bit) {
            if (!((key >> bit) & 1)) continue;
            if (!have) {
                if (tid < 256) Vc[tid] = CH[bit*256 + tid];
                have = true;
                LDS_BAR();
            } else {
                float v = 0.f;
                if (tid < 256) {
                    #pragma unroll
                    for (int m = 0; m < NS; ++m)
                        v += Vc[r16*16+m] * CH[bit*256 + m*16+c16];
                }
                LDS_BAR();
                if (tid < 256) Vn[tid] = v;
                LDS_BAR();
                float* tt = Vc; Vc = Vn; Vn = tt;
            }
        }
        if (tid < 256) {
            const float val = have ? Vc[tid] : ident;
            if (isP) ws[OFF_P + (key-1)*256 + tid] = val;
            else     ws[OFF_Q + key*256 + tid]     = val;
        }
    }
}

// ---------- K2: cin via Q-table sum (32 groups), correction, out-GEMM ----------
// (round-11/15/17/19 proven, unchanged)
__global__ __launch_bounds__(512, 4) void k2_kernel(const float* __restrict__ C,
                                                    const float* __restrict__ state,
                                                    const float* __restrict__ ws,
                                                    float* __restrict__ out) {
    __shared__ __align__(16) float st[32*20];     // padded stride 20
    __shared__ float vec[(NCH+1)*16];             // lend_0..c-1, state0
    __shared__ float part[32*17];
    __shared__ float cin_s[16];
    const int tid = threadIdx.x;
    const int row0 = blockIdx.x * 32;
    const int b = row0 >> 12, cch = (row0 >> 5) & (NCH-1);

    if (tid < 128) {
        const int j = tid >> 2, n4 = (tid & 3)*4;
        *(float4*)(&st[j*20 + n4]) =
            *(const float4*)(ws + OFF_U + (size_t)(row0 + j)*16 + n4);
    }
    for (int i = tid; i < cch*16; i += 512)
        vec[i] = ws[OFF_LEND + b*NCH*16 + i];
    if (tid < 16) vec[cch*16 + tid] = state[b*16 + tid];
    __syncthreads();

    {
        const int g = tid >> 4, n2 = tid & 15;
        float p = 0.f;
        for (int j = g; j <= cch; j += 32) {
            const int qidx = (j == cch) ? cch : (cch - 1 - j);
            const float* Q = ws + OFF_Q + qidx*256;
            float sv = 0.f;
            #pragma unroll
            for (int m = 0; m < NS; ++m) sv += vec[j*16 + m] * Q[m*16 + n2];
            p += sv;
        }
        part[g*17 + n2] = p;
    }
    __syncthreads();
    for (int s2 = 16; s2 > 0; s2 >>= 1) {
        if ((tid >> 4) < s2)
            part[(tid>>4)*17 + (tid&15)] += part[((tid>>4)+s2)*17 + (tid&15)];
        __syncthreads();
    }
    if (tid < 16) cin_s[tid] = part[tid];
    __syncthreads();

    if (tid < 128) {
        const int j = tid >> 2, n4 = (tid & 3)*4;
        float4 ls = *(const float4*)(&st[j*20 + n4]);
        const float* P = ws + OFF_P + j*256 + n4;
        float cx=0.f, cy=0.f, cz=0.f, cw=0.f;
        #pragma unroll
        for (int m = 0; m < NS; ++m) {
            const float cm = cin_s[m];
            float4 pv = *(const float4*)(P + m*16);
            cx += cm*pv.x; cy += cm*pv.y; cz += cm*pv.z; cw += cm*pv.w;
        }
        *(float4*)(&st[j*20 + n4]) = make_float4(ls.x+cx, ls.y+cy, ls.z+cz, ls.w+cw);
    }
    __syncthreads();
    if (cch == NCH-1 && tid < 16)
        out[(size_t)ROWS*HID + b*16 + tid] = st[31*20 + tid];

    const int w = tid >> 6, lane = tid & 63;
    const int rhalf = w & 1, cg = w >> 1;
    const int lr = lane & 15;
    const int hi = lane >> 4;
    const int lk = hi * 8;

    v8bf afr = {};
    if (lk < 16) {
        float4 s0 = *(const float4*)(&st[(rhalf*16 + lr)*20 + lk]);
        float4 s1 = *(const float4*)(&st[(rhalf*16 + lr)*20 + lk + 4]);
        afr[0]=(__bf16)s0.x; afr[1]=(__bf16)s0.y; afr[2]=(__bf16)s0.z; afr[3]=(__bf16)s0.w;
        afr[4]=(__bf16)s1.x; afr[5]=(__bf16)s1.y; afr[6]=(__bf16)s1.z; afr[7]=(__bf16)s1.w;
    }
    const int orow = row0 + rhalf*16 + hi*4;

    float4 pc0, pc1;
    {
        const int n0 = (cg*16)*16;
        if (lk < 16) {
            pc0 = *(const float4*)(C + (size_t)(n0 + lr)*16 + lk);
            pc1 = *(const float4*)(C + (size_t)(n0 + lr)*16 + lk + 4);
        }
    }
    #pragma unroll 4
    for (int nt = 0; nt < 16; ++nt) {
        const int n0 = (cg*16 + nt)*16;
        float4 c0 = pc0, c1 = pc1;
        if (nt + 1 < 16 && lk < 16) {
            const int n1 = (cg*16 + nt + 1)*16;
            pc0 = *(const float4*)(C + (size_t)(n1 + lr)*16 + lk);
            pc1 = *(const float4*)(C + (size_t)(n1 + lr)*16 + lk + 4);
        }
        v8bf bfr = {};
        if (lk < 16) {
            bfr[0]=(__bf16)c0.x; bfr[1]=(__bf16)c0.y; bfr[2]=(__bf16)c0.z; bfr[3]=(__bf16)c0.w;
            bfr[4]=(__bf16)c1.x; bfr[5]=(__bf16)c1.y; bfr[6]=(__bf16)c1.z; bfr[7]=(__bf16)c1.w;
        }
        f32x4 acc2 = {0.f, 0.f, 0.f, 0.f};
        acc2 = __builtin_amdgcn_mfma_f32_16x16x32_bf16(afr, bfr, acc2, 0, 0, 0);
        #pragma unroll
        for (int rg = 0; rg < 4; ++rg)
            out[(size_t)(orow + rg)*HID + n0 + lr] = acc2[rg];
    }
}

extern "C" void kernel_launch(void* const* d_in, const int* in_sizes, int n_in,
                              void* d_out, int out_size, void* d_ws, size_t ws_size,
                              hipStream_t stream) {
    (void)in_sizes; (void)n_in; (void)out_size; (void)ws_size;
    const float* x      = (const float*)d_in[0];
    const float* state  = (const float*)d_in[1];
    const float* A      = (const float*)d_in[2];
    const float* B      = (const float*)d_in[3];
    const float* C      = (const float*)d_in[4];
    const float* log_dt = (const float*)d_in[5];
    float* out = (float*)d_out;
    float* ws  = (float*)d_ws;

    k1_fused<<<ROWS/32, 512, 0, stream>>>(x, A, B, log_dt, ws);
    k2_kernel<<<ROWS/32, 512, 0, stream>>>(C, state, ws, out);
}